// Round 8
// baseline (409.785 us; speedup 1.0000x reference)
//
#include <hip/hip_runtime.h>

// ---------------------------------------------------------------------------
// MAF forward log-prob, fully fused. D=45, H=256, NB=6, L=2, K=8, M=23.
// R8 (= R7 with compile fix): 32 rows / 512-thr WG, 8 waves x one 32-col tile:
//  - __launch_bounds__(512,6): ~80 VGPR budget -> no scratch spills
//  - CH=4 weight bursts
//  - pbuf double-buffered: Wf-gemm(g) + spline(g-1) share one barrier
//    (barriers/block 15 -> 11). LDS 50944 B -> 3 WGs/CU (24 waves).
//  - fix: LDS pointer selected via byte-offset arithmetic, NOT a local
//    pointer array (addrspacecast static-initializer error on gfx950).
// ---------------------------------------------------------------------------

typedef __bf16 bf16;
typedef __bf16 bf16x8 __attribute__((ext_vector_type(8)));
typedef float  f32x4  __attribute__((ext_vector_type(4)));
typedef float  f32x16 __attribute__((ext_vector_type(16)));

#define TAILF  13.815510557964274f      /* -log(1e-6) */
#define LOGZ   41.352233994210265f      /* 0.5*45*log(2*pi) */

// ---------------- workspace layout (bytes) ----------------
// Packed weight chunks: chunk (tile t, kt) = 512 bf16; element (lane,j) =
// W[col = t*32 + (lane&31)][k = kt*16 + (lane>>5)*8 + j].
#define WS_W0M   0            /* bf16 [6][8 t][3 kt][512]    147456 */
#define WS_WHM   147456       /* bf16 [12][8 t][16 kt][512]  1572864 */
#define WS_WFM   1720320      /* bf16 [30][7 t][16 kt][512]  3440640 */
#define WS_BEFF  5160960      /* f32  [6][256]   6144 */
#define WS_BFP   5167104      /* f32  [30][224]  26880 (stride-24 features) */
#define WS_WCC   5193984      /* f32  [6][256]   6144 */
#define WS_NEED  5200128

#define N_W0  (6*8*3*512)       /* 73728   */
#define N_WH  (6*2*256*256)     /* 786432  */
#define N_WF  (30*7*16*512)     /* 1720320 */
#define N_PREP (N_W0 + N_WH + N_WF)

// ---------------- merged prep kernel (mask + cast + fragment-pack) ---------
__global__ void prep_all(const float* __restrict__ W0, const float* __restrict__ b0,
                         const float* __restrict__ Wc, const float* __restrict__ bc,
                         const float* __restrict__ Wh, const float* __restrict__ Wf,
                         const float* __restrict__ bfv,
                         bf16* __restrict__ W0m, bf16* __restrict__ Whm,
                         bf16* __restrict__ Wfm,
                         float* __restrict__ beff, float* __restrict__ bfp,
                         float* __restrict__ Wcc)
{
    int idx = blockIdx.x * 256 + threadIdx.x;
    if (idx < N_W0) {
        // [b][t=8][kt=3][512]
        int j = idx & 7, lane = (idx >> 3) & 63, chunk = idx >> 9;
        int kt = chunk % 3, t = (chunk / 3) & 7, b = chunk / 24;
        int col = t * 32 + (lane & 31);
        int k   = kt * 16 + (lane >> 5) * 8 + j;
        float v = 0.f;
        if (k < 45 && (col % 44) >= k)                 // m0: deg_h[col] >= k+1
            v = W0[(b * 256 + col) * 45 + k];
        W0m[idx] = (bf16)v;
        if (k == 0) {
            beff[b * 256 + col] = b0[b * 256 + col] + bc[b * 256 + col];
            Wcc[b * 256 + col]  = Wc[b * 256 + col];
        }
    } else if (idx < N_W0 + N_WH) {
        // [bl][t=8][kt=16][512]
        int id = idx - N_W0;
        int j = id & 7, lane = (id >> 3) & 63, chunk = id >> 9;
        int kt = chunk & 15, t = (chunk >> 4) & 7, bl = chunk >> 7;
        int col = t * 32 + (lane & 31);
        int k   = kt * 16 + (lane >> 5) * 8 + j;
        float v = ((col % 44) >= (k % 44)) ? Wh[bl * 65536 + col * 256 + k] : 0.f;
        Whm[id] = (bf16)v;
    } else if (idx < N_PREP) {
        // [bg][t=7][kt=16][512]; col 0..223; f = 9g + col/24, m = col%24
        int id = idx - (N_W0 + N_WH);
        int j = id & 7, lane = (id >> 3) & 63, chunk = id >> 9;
        int kt = chunk & 15, t2 = chunk >> 4;
        int t  = t2 % 7, bg = t2 / 7;                  // bg = b*5+g
        int b  = bg / 5, g = bg - 5 * b;
        int col = t * 32 + (lane & 31);
        int k   = kt * 16 + (lane >> 5) * 8 + j;
        int f   = 9 * g + col / 24;
        int m   = col - (col / 24) * 24;
        bool valid = (col < 216) && (m < 23);
        float v = 0.f;
        if (valid && (f > (k % 44)))                   // mf strict
            v = Wf[(b * 1035 + f * 23 + m) * 256 + k];
        Wfm[id] = (bf16)v;
        if (k == 0)
            bfp[bg * 224 + col] = valid ? bfv[b * 1035 + f * 23 + m] : 0.f;
    }
}

// ---------------- fused main kernel ----------------
// LDS (dynamic, 50944 B -> 3 blocks/CU):
#define SO_ZF    0        /* float [32][48]   6144 (cols 45..47 = 0) */
#define SO_HIDA  6144     /* bf16  [32][264] 16896 */
#define SO_PBUF0 23040    /* bf16  [32][216] 13824 (stride-24 features) */
#define PBUF_SZ  13824    /* second buffer at SO_PBUF0 + PBUF_SZ */
#define SO_COND  50688    /* float [32] */
#define SO_LD    50816    /* float [32] */
#define SMEM_BYTES 50944

// GEMM: out[32 rows][NT*32 cols] = act[32][KT*16] @ W^T (+epilogue).
// 8 waves, wave w owns col tile w (32 cols), all 32 rows in one acc.
// arg0 = act frag (LDS b128 / f32-built): A[m=lane&31][k=(lane>>5)*8+j];
// arg1 = weight chunk (coalesced global, lane*16B);
// D: col(n)=lane&31, row(m)=(r&3)+8*(r>>2)+4*(lane>>5).
// MODE 0: +bias+cond[row]*wcol; MODE 1: +bias, relu; MODE 2: +bias.
template<int KT, int NT, int MODE, bool F32B, int LIMIT>
__device__ __forceinline__ void gemm32(
    const void* Act, int lda,
    const bf16* __restrict__ Wp,
    const float* __restrict__ bias, const float* __restrict__ wcol,
    const float* condl, bf16* dst, int ldd,
    int w, int lane, bool preEpiSync, bool postSync)
{
    const bool act = (NT == 8) || (w < NT);
    const int  l31 = lane & 31;
    const int  q   = lane >> 5;

    const bf16*  Ab = (const bf16*)Act + l31 * lda + q * 8;
    const float* Af = (const float*)Act + l31 * lda + q * 8;
    const bf16*  Bp = Wp + (size_t)w * KT * 512 + lane * 8;

    f32x16 acc = {};
    constexpr int CH = (KT < 4) ? KT : 4;
    #pragma unroll
    for (int kb = 0; kb < KT / CH; ++kb) {
        bf16x8 wq[CH];
        if (act) {
            #pragma unroll
            for (int c = 0; c < CH; ++c)
                wq[c] = *reinterpret_cast<const bf16x8*>(Bp + (kb * CH + c) * 512);
            #pragma unroll
            for (int c = 0; c < CH; ++c) {
                const int kt = kb * CH + c;
                bf16x8 af;
                if constexpr (F32B) {
                    f32x4 fa = *reinterpret_cast<const f32x4*>(Af + kt * 16);
                    f32x4 fb = *reinterpret_cast<const f32x4*>(Af + kt * 16 + 4);
                    af = (bf16x8){(bf16)fa[0], (bf16)fa[1], (bf16)fa[2], (bf16)fa[3],
                                  (bf16)fb[0], (bf16)fb[1], (bf16)fb[2], (bf16)fb[3]};
                } else {
                    af = *reinterpret_cast<const bf16x8*>(Ab + kt * 16);
                }
                acc = __builtin_amdgcn_mfma_f32_32x32x16_bf16(af, wq[c], acc, 0, 0, 0);
            }
        }
    }

    if (preEpiSync) __syncthreads();   // in-place layers: all act reads done

    if (act) {
        const int col = w * 32 + l31;
        if (LIMIT == 256 || col < LIMIT) {
            const float bv  = bias[col];
            const float wcv = (MODE == 0) ? wcol[col] : 0.f;
            bf16* dcol = dst + col;
            #pragma unroll
            for (int r = 0; r < 16; ++r) {
                const int row = (r & 3) + 8 * (r >> 2) + 4 * q;
                float v = acc[r] + bv;
                if (MODE == 0) v += condl[row] * wcv;
                if (MODE == 1) v = fmaxf(v, 0.f);
                dcol[row * ldd] = (bf16)v;
            }
        }
    }
    if (postSync) __syncthreads();
}

// RQ spline, low-register form: fused cumsum+select scans, ~25 live floats.
// Params in pbuf (row stride 216, feature stride 24 -> 3x ds_read_b128).
__device__ __forceinline__ void do_spline(int fb, float* zf,
                                          const bf16* pbuf, float* ldl, int t)
{
    if (t < 32 * 9) {
        int r  = t / 9;
        int fl = t - r * 9;
        const bf16* pp = pbuf + r * 216 + fl * 24;

        float xin = zf[r * 48 + fb + fl];
        float xc  = fminf(fmaxf(xin, -TAILF), TAILF);
        bool inside = (xin >= -TAILF) && (xin <= TAILF);

        // ---- widths: softmax(P/16) (no max-sub: |P|<<1), scan + bin select
        bf16x8 p0 = *reinterpret_cast<const bf16x8*>(pp);
        float ew[8], sw = 0.f;
        #pragma unroll
        for (int i = 0; i < 8; ++i) {
            ew[i] = __expf((float)p0[i] * 0.0625f); sw += ew[i];
        }
        float rws = 0.992f * __frcp_rn(sw);
        int   idx = 0;
        float icw = -TAILF, ibw = 1.f;
        {
            float left = -TAILF;
            #pragma unroll
            for (int i = 0; i < 8; ++i) {
                float wi = (i < 7) ? 2.f * TAILF * (1e-3f + ew[i] * rws)
                                   : (TAILF - left);
                bool ge = (xc >= left);          // left == cw[i] here
                idx = ge ? i : idx;
                icw = ge ? left : icw;
                ibw = ge ? wi : ibw;
                left += wi;
            }
        }

        // ---- heights: same scan, select bin i == idx
        bf16x8 p1 = *reinterpret_cast<const bf16x8*>(pp + 8);
        float eh[8], sh = 0.f;
        #pragma unroll
        for (int i = 0; i < 8; ++i) {
            eh[i] = __expf((float)p1[i] * 0.0625f); sh += eh[i];
        }
        float rhs = 0.992f * __frcp_rn(sh);
        float ich = -TAILF, ibh = 1.f;
        {
            float left = -TAILF;
            #pragma unroll
            for (int i = 0; i < 8; ++i) {
                float hi = (i < 7) ? 2.f * TAILF * (1e-3f + eh[i] * rhs)
                                   : (TAILF - left);
                bool eq = (i == idx);
                ich = eq ? left : ich;
                ibh = eq ? hi : ibh;
                left += hi;
            }
        }

        // ---- derivatives: d[0]=d[8]=1 (pad), interior 1e-3+softplus
        bf16x8 p2 = *reinterpret_cast<const bf16x8*>(pp + 16);
        float id0 = 1.f, id1 = 1.f;
        #pragma unroll
        for (int i = 1; i < 8; ++i) {
            float di = 1e-3f + __logf(1.f + __expf((float)p2[i - 1]));
            id0 = (i == idx) ? di : id0;
            id1 = (i == idx + 1) ? di : id1;
        }

        float ribw = __frcp_rn(ibw);
        float th   = (xc - icw) * ribw;
        float th1  = th * (1.f - th);
        float dl   = ibh * ribw;
        float den  = dl + (id0 + id1 - 2.f * dl) * th1;
        float rden = __frcp_rn(den);
        float yy   = ich + ibh * (dl * th * th + id0 * th1) * rden;
        float num  = dl * dl * (id1 * th * th + 2.f * dl * th1
                                + id0 * (1.f - th) * (1.f - th));
        float lad  = __logf(num * rden * rden);

        if (inside) {
            zf[r * 48 + fb + fl] = yy;
            atomicAdd(&ldl[r], lad);
        }
    }
}

__global__ __launch_bounds__(512, 6) void maf_main(
    const float* __restrict__ x, const float* __restrict__ cond,
    const float* __restrict__ bh_all,
    const bf16* __restrict__ W0m, const bf16* __restrict__ Whm,
    const bf16* __restrict__ Wfm,
    const float* __restrict__ beff, const float* __restrict__ bfp,
    const float* __restrict__ Wcc,
    float* __restrict__ out, int B)
{
    extern __shared__ char smem[];
    float* zf    = (float*)(smem + SO_ZF);
    bf16*  hidA  = (bf16*)(smem + SO_HIDA);
    float* condl = (float*)(smem + SO_COND);
    float* ldl   = (float*)(smem + SO_LD);
    // pbuf selected via byte-offset arithmetic (no local pointer array:
    // addrspacecast static-initializer is unsupported on gfx950)
    #define PBUF(sel) ((bf16*)(smem + SO_PBUF0 + (sel) * PBUF_SZ))

    const int t    = threadIdx.x;
    const int r0   = blockIdx.x * 32;
    const int w    = t >> 6;
    const int lane = t & 63;

    // init: zf (pad cols 45..47 = 0), cond, ld
    for (int i = t; i < 32 * 48; i += 512) {
        int r = i / 48, c = i - (i / 48) * 48;
        float v = 0.f;
        if (c < 45 && r0 + r < B) v = x[(size_t)(r0 + r) * 45 + c];
        zf[i] = v;
    }
    if (t < 32) {
        condl[t] = (r0 + t < B) ? cond[r0 + t] : 0.f;
        ldl[t]   = 0.f;
    }
    __syncthreads();

    #pragma unroll 1
    for (int b = 0; b < 6; ++b) {
        // input MADE layer: K=48 (padded from 45), A-frags from zf (f32)
        gemm32<3, 8, 0, true, 256>(zf, 48, W0m + b * 12288,
                                   beff + b * 256, Wcc + b * 256, condl,
                                   hidA, 264, w, lane, false, true);
        // 2 hidden layers, relu, in-place
        #pragma unroll 1
        for (int l = 0; l < 2; ++l)
            gemm32<16, 8, 1, false, 256>(hidA, 264, Whm + (b * 2 + l) * 65536,
                                         bh_all + (b * 2 + l) * 256, nullptr,
                                         nullptr, hidA, 264, w, lane, true, true);
        // params: 5 groups x 9 features, pbuf double-buffered; Wf-gemm(g)
        // and spline(g-1) share one barrier (different buffers; spline
        // writes zf which Wf-gemm never reads).
        gemm32<16, 7, 2, false, 216>(hidA, 264, Wfm + (size_t)(b * 5) * 57344,
                                     bfp + (b * 5) * 224, nullptr,
                                     nullptr, PBUF(0), 216, w, lane, false, true);
        #pragma unroll 1
        for (int g = 1; g < 5; ++g) {
            gemm32<16, 7, 2, false, 216>(hidA, 264,
                                         Wfm + (size_t)(b * 5 + g) * 57344,
                                         bfp + (b * 5 + g) * 224, nullptr,
                                         nullptr, PBUF(g & 1), 216, w, lane,
                                         false, false);
            do_spline((g - 1) * 9, zf, PBUF((g - 1) & 1), ldl, t);
            __syncthreads();
        }
        do_spline(4 * 9, zf, PBUF(0), ldl, t);
        __syncthreads();
    }

    if (t < 32 && r0 + t < B) {
        float s = 0.f;
        #pragma unroll
        for (int f = 0; f < 45; ++f) { float v = zf[t * 48 + f]; s += v * v; }
        out[r0 + t] = -0.5f * s - LOGZ + ldl[t];
    }
    #undef PBUF
}

// ---------------- host entry ----------------
extern "C" void kernel_launch(void* const* d_in, const int* in_sizes, int n_in,
                              void* d_out, int out_size, void* d_ws, size_t ws_size,
                              hipStream_t stream)
{
    const float* x    = (const float*)d_in[0];
    const float* cond = (const float*)d_in[1];
    const float* W0   = (const float*)d_in[2];
    const float* b0   = (const float*)d_in[3];
    const float* Wc   = (const float*)d_in[4];
    const float* bc   = (const float*)d_in[5];
    const float* Wh   = (const float*)d_in[6];
    const float* bh   = (const float*)d_in[7];
    const float* Wf   = (const float*)d_in[8];
    const float* bfv  = (const float*)d_in[9];
    float* out = (float*)d_out;

    const int B = in_sizes[0] / 45;
    if (ws_size < (size_t)WS_NEED) return;   // fail loudly

    char* ws = (char*)d_ws;
    bf16*  W0m  = (bf16*)(ws + WS_W0M);
    bf16*  Whm  = (bf16*)(ws + WS_WHM);
    bf16*  Wfm  = (bf16*)(ws + WS_WFM);
    float* beff = (float*)(ws + WS_BEFF);
    float* bfp  = (float*)(ws + WS_BFP);
    float* Wcc  = (float*)(ws + WS_WCC);

    prep_all<<<(N_PREP + 255) / 256, 256, 0, stream>>>(
        W0, b0, Wc, bc, Wh, Wf, bfv, W0m, Whm, Wfm, beff, bfp, Wcc);

    (void)hipFuncSetAttribute((const void*)maf_main,
                              hipFuncAttributeMaxDynamicSharedMemorySize,
                              SMEM_BYTES);

    const int nwg = (B + 31) / 32;
    maf_main<<<nwg, 512, SMEM_BYTES, stream>>>(
        x, cond, bh, W0m, Whm, Wfm, beff, bfp, Wcc, out, B);
}